// Round 3
// baseline (506.740 us; speedup 1.0000x reference)
//
#include <hip/hip_runtime.h>
#include <cstdint>
#include <cstddef>

// Problem constants: B=64, T=2048, M=512, P=512

typedef float  floatx4 __attribute__((ext_vector_type(4)));
typedef short  shortx8 __attribute__((ext_vector_type(8)));
typedef unsigned int uintx4 __attribute__((ext_vector_type(4)));

__device__ __forceinline__ short f2bf_rne(float f) {
  unsigned u = __float_as_uint(f);
  unsigned r = u + 0x7FFFu + ((u >> 16) & 1u);
  return (short)(r >> 16);
}

// pack two fp32 -> two bf16 (truncation) in one v_perm_b32
__device__ __forceinline__ unsigned pack_bf_trunc(float lo, float hi) {
  return __builtin_amdgcn_perm(__float_as_uint(hi), __float_as_uint(lo), 0x07060302u);
}

#define GLOAD_LDS16(gptr, lptr)                                                 \
  __builtin_amdgcn_global_load_lds(                                             \
      (const __attribute__((address_space(1))) void*)(gptr),                    \
      (__attribute__((address_space(3))) void*)(lptr), 16, 0, 0)

#define SB() __builtin_amdgcn_sched_barrier(0)
#define WAIT_VM0() asm volatile("s_waitcnt vmcnt(0)" ::: "memory")
#define WAIT_VM4() asm volatile("s_waitcnt vmcnt(4)" ::: "memory")
#define WAIT_VM8() asm volatile("s_waitcnt vmcnt(8)" ::: "memory")
#define WAIT_LGKM0() asm volatile("s_waitcnt lgkmcnt(0)" ::: "memory")
#define BAR() __builtin_amdgcn_s_barrier()

// ---------------------------------------------------------------------------
// Kernel 1: prep.
//   blocks 0..127:   S[b][n] = ds@W_d + b_wd + b_ud  (fp32), 4-way ILP
//   blocks 128..383: UT = pre-swizzled bf16 LDS byte-image of U_d^T for BK=64:
//                    16 tiles (cb*8+kt) of 16384 shorts: [n 0..255][8 granules
//                    of 16B]; physical granule gp holds logical gl = gp^(n&7),
//                    i.e. k = kt*64 + gl*8 + 0..7, col = cb*256+n.
//   blocks 384..511: zero d_out (logit accumulator)
// ---------------------------------------------------------------------------
extern "C" __global__ __launch_bounds__(256) void prep_kernel(
    const float* __restrict__ hidden, const float* __restrict__ cell,
    const float* __restrict__ W_d, const float* __restrict__ b_wd,
    const float* __restrict__ U_d, const float* __restrict__ b_ud,
    float* __restrict__ S, short* __restrict__ UT, float* __restrict__ lzero)
{
  int bx = blockIdx.x, tid = threadIdx.x;
  if (bx < 128) {
    int idx = bx * 256 + tid;          // 0..32767
    int b = idx >> 9, n = idx & 511;
    const float* h = hidden + b * 512;
    const float* c = cell   + b * 512;
    float a0 = b_wd[n] + b_ud[n], a1 = 0.f, a2 = 0.f, a3 = 0.f;
    for (int k = 0; k < 512; k += 4) {
      a0 = fmaf(h[k + 0], W_d[(k + 0) * 512 + n], a0);
      a1 = fmaf(h[k + 1], W_d[(k + 1) * 512 + n], a1);
      a2 = fmaf(h[k + 2], W_d[(k + 2) * 512 + n], a2);
      a3 = fmaf(h[k + 3], W_d[(k + 3) * 512 + n], a3);
    }
    for (int k = 0; k < 512; k += 4) {
      a0 = fmaf(c[k + 0], W_d[(k + 512) * 512 + n], a0);
      a1 = fmaf(c[k + 1], W_d[(k + 513) * 512 + n], a1);
      a2 = fmaf(c[k + 2], W_d[(k + 514) * 512 + n], a2);
      a3 = fmaf(c[k + 3], W_d[(k + 515) * 512 + n], a3);
    }
    S[idx] = (a0 + a1) + (a2 + a3);
  } else if (bx < 384) {
    int idx  = (bx - 128) * 1024 + tid * 4;  // short index into UT image
    int tile = idx >> 14;                    // 0..15 = cb*8 + kt
    int cb = tile >> 3, kt = tile & 7;
    int sI = idx & 16383;
    int n  = sI >> 6;                        // 0..255
    int gp = (sI >> 3) & 7;                  // physical 16B granule
    int bb = sI & 7;                         // 0 or 4
    int gl = gp ^ (n & 7);                   // logical granule
    int k0 = kt * 64 + gl * 8 + bb;
    int ng = cb * 256 + n;
    unsigned lo = (unsigned short)f2bf_rne(U_d[(size_t)(k0 + 0) * 512 + ng]) |
                  ((unsigned)(unsigned short)f2bf_rne(U_d[(size_t)(k0 + 1) * 512 + ng]) << 16);
    unsigned hi = (unsigned short)f2bf_rne(U_d[(size_t)(k0 + 2) * 512 + ng]) |
                  ((unsigned)(unsigned short)f2bf_rne(U_d[(size_t)(k0 + 3) * 512 + ng]) << 16);
    uint2 w; w.x = lo; w.y = hi;
    *(uint2*)(UT + idx) = w;
  } else {
    int idx = ((bx - 384) * 256 + tid) * 4;
    floatx4 z = {0.f, 0.f, 0.f, 0.f};
    *(floatx4*)(lzero + idx) = z;
  }
}

// ---------------------------------------------------------------------------
// Kernel 2: fused GEMM + tanh + dot(v) -> atomicAdd partial logits.
// m201-style: 256x256 tile, BK=64, 8 waves (2x4, 128x64 each), 4 MFMA-phases
// of 16 per K-tile, per-phase barrier pairs, setprio, counted vmcnt (never 0
// mid-loop).  A: fp32 -> regs (1-iter prefetch) -> bf16 pack -> swizzled
// ds_write_b128.  B: pre-swizzled image -> linear global_load_lds.
// Outer loop unroll 2 (static cur per copy) to bound compile size.
// ---------------------------------------------------------------------------
extern "C" __global__ __launch_bounds__(512, 2) void attn_gemm(
    const float* __restrict__ A, const short* __restrict__ UT,
    const float* __restrict__ S, const float* __restrict__ vd,
    float* __restrict__ lout)
{
  __shared__ short As[2][16384];   // [buf][256 rows][64 k] bf16 swizzled, 32 KB
  __shared__ short Bs[2][16384];   // [buf][256 n   ][64 k] bf16 swizzled, 32 KB

  const int tid = threadIdx.x;
  const int bx  = blockIdx.x;
  // XCD swizzle: 1024 blocks, 128/XCD; col-block pairs adjacent on one XCD.
  const int xcd = bx & 7;
  const int wg  = xcd * 128 + (bx >> 3);
  const int cb  = wg & 1;
  const int rb  = wg >> 1;           // 0..511
  const int row0 = rb << 8;
  const int col0 = cb << 8;
  const int wave = tid >> 6;
  const int lane = tid & 63;
  const int wr = wave >> 2, wc = wave & 3;   // 2 x 4 wave grid
  const int q = lane >> 4, l15 = lane & 15;

  // --- A staging: thread owns row tid>>1, k-half tid&1 (8 float4 / K-tile) ---
  const int arow = tid >> 1;
  const int ah   = tid & 1;
  const float* aptr = A + (size_t)(row0 + arow) * 512 + ah * 32;
  // LDS write base (shorts); granule gi XORed in at write time (gi in low bits)
  const int awbase = arow * 64 + ((((ah * 4) ^ (arow & 7)) & 7) << 3);

  // --- B staging: 4 glds shots of 1 KB per wave per K-tile ---
  const short* bptr = UT + (size_t)cb * 131072 + (wave * 4) * 512 + lane * 8;
  const int bldsbase = wave * 2048;

  // --- fragment read bases (shorts); (row&7) == (l15&7) for all tr/tc ---
  const int fgp = (q ^ (l15 & 7)) << 3;
  const int afrag0 = (wr * 128 + l15) * 64 + fgp;   // + tr*1024, ^32 for s=1
  const int bfrag0 = (wc * 64  + l15) * 64 + fgp;   // + tc*1024, ^32 for s=1

  floatx4 acc[8][4];
#pragma unroll
  for (int i = 0; i < 8; ++i)
#pragma unroll
    for (int j = 0; j < 4; ++j)
      acc[i][j] = (floatx4){0.f, 0.f, 0.f, 0.f};

  floatx4 areg[8];

  // ------------------- prologue -------------------
  SB();
#pragma unroll
  for (int i = 0; i < 8; ++i) areg[i] = *(const floatx4*)(aptr + i * 4);  // A(0)
  SB();
#pragma unroll
  for (int j = 0; j < 4; ++j)
    GLOAD_LDS16(bptr + j * 512, &Bs[0][bldsbase + j * 512]);              // B(0)
  SB();
  WAIT_VM4(); SB();                  // A(0) landed; B(0) still in flight
#pragma unroll
  for (int gi = 0; gi < 4; ++gi) {
    uintx4 w;
    w.x = pack_bf_trunc(areg[2 * gi].x, areg[2 * gi].y);
    w.y = pack_bf_trunc(areg[2 * gi].z, areg[2 * gi].w);
    w.z = pack_bf_trunc(areg[2 * gi + 1].x, areg[2 * gi + 1].y);
    w.w = pack_bf_trunc(areg[2 * gi + 1].z, areg[2 * gi + 1].w);
    *(uintx4*)(&As[0][awbase ^ (gi * 8)]) = w;
  }
  SB();
#pragma unroll
  for (int i = 0; i < 8; ++i) areg[i] = *(const floatx4*)(aptr + 64 + i * 4); // A(1)
  SB();
  WAIT_VM8(); SB();                  // B(0) done; A(1)x8 in flight
  WAIT_LGKM0(); SB();
  BAR(); SB();

  shortx8 af[4][2], bfr[4][2];

  // ------------------- main loop: 8 K-tiles of 64 -------------------
#pragma unroll 2
  for (int t = 0; t < 8; ++t) {
    const int cur = t & 1;
    const short* Ab = &As[cur][0];
    const short* Bb = &Bs[cur][0];
    short* An = &As[cur ^ 1][0];
    short* Bn = &Bs[cur ^ 1][0];
    const short* bnext = bptr + (t + 1) * 16384;

    // ---- phase 0: bfr tc0..1, af tr0..3; issue B(t+1) shots 0,1 ----
#pragma unroll
    for (int tc = 0; tc < 2; ++tc)
#pragma unroll
      for (int s = 0; s < 2; ++s)
        bfr[tc][s] = *(const shortx8*)(Bb + ((bfrag0 + tc * 1024) ^ (s * 32)));
#pragma unroll
    for (int tr = 0; tr < 4; ++tr)
#pragma unroll
      for (int s = 0; s < 2; ++s)
        af[tr][s] = *(const shortx8*)(Ab + ((afrag0 + tr * 1024) ^ (s * 32)));
    SB();
    if (t < 7) {
      GLOAD_LDS16(bnext,       Bn + bldsbase);
      GLOAD_LDS16(bnext + 512, Bn + bldsbase + 512);
    }
    SB();
    BAR(); WAIT_LGKM0(); SB();
    __builtin_amdgcn_s_setprio(1);
#pragma unroll
    for (int tr = 0; tr < 4; ++tr)
#pragma unroll
      for (int tc = 0; tc < 2; ++tc)
#pragma unroll
        for (int s = 0; s < 2; ++s)
          acc[tr][tc] = __builtin_amdgcn_mfma_f32_16x16x32_bf16(
              af[tr][s], bfr[tc][s], acc[tr][tc], 0, 0, 0);
    __builtin_amdgcn_s_setprio(0);
    SB(); BAR();

    // ---- phase 1: bfr tc2..3; issue B(t+1) shots 2,3 ----
#pragma unroll
    for (int tc = 2; tc < 4; ++tc)
#pragma unroll
      for (int s = 0; s < 2; ++s)
        bfr[tc][s] = *(const shortx8*)(Bb + ((bfrag0 + tc * 1024) ^ (s * 32)));
    SB();
    if (t < 7) {
      GLOAD_LDS16(bnext + 1024, Bn + bldsbase + 1024);
      GLOAD_LDS16(bnext + 1536, Bn + bldsbase + 1536);
    }
    SB();
    BAR(); WAIT_LGKM0(); SB();
    __builtin_amdgcn_s_setprio(1);
#pragma unroll
    for (int tr = 0; tr < 4; ++tr)
#pragma unroll
      for (int tc = 2; tc < 4; ++tc)
#pragma unroll
        for (int s = 0; s < 2; ++s)
          acc[tr][tc] = __builtin_amdgcn_mfma_f32_16x16x32_bf16(
              af[tr][s], bfr[tc][s], acc[tr][tc], 0, 0, 0);
    __builtin_amdgcn_s_setprio(0);
    SB(); BAR();

    // ---- phase 2: consume A(t+1) regs -> LDS; af tr4..7; issue A(t+2) ----
    if (t < 7) {
      WAIT_VM4(); SB();              // A(t+1) done; B(t+1)x4 in flight
#pragma unroll
      for (int gi = 0; gi < 4; ++gi) {
        uintx4 w;
        w.x = pack_bf_trunc(areg[2 * gi].x, areg[2 * gi].y);
        w.y = pack_bf_trunc(areg[2 * gi].z, areg[2 * gi].w);
        w.z = pack_bf_trunc(areg[2 * gi + 1].x, areg[2 * gi + 1].y);
        w.w = pack_bf_trunc(areg[2 * gi + 1].z, areg[2 * gi + 1].w);
        *(uintx4*)(An + (awbase ^ (gi * 8))) = w;
      }
      SB();
    }
#pragma unroll
    for (int tr = 0; tr < 4; ++tr)
#pragma unroll
      for (int s = 0; s < 2; ++s)
        af[tr][s] = *(const shortx8*)(Ab + ((afrag0 + (tr + 4) * 1024) ^ (s * 32)));
    SB();
    if (t < 6) {
#pragma unroll
      for (int i = 0; i < 8; ++i)
        areg[i] = *(const floatx4*)(aptr + (t + 2) * 64 + i * 4);   // A(t+2)
    }
    SB();
    BAR(); WAIT_LGKM0(); SB();
    __builtin_amdgcn_s_setprio(1);
#pragma unroll
    for (int tr = 0; tr < 4; ++tr)
#pragma unroll
      for (int tc = 0; tc < 2; ++tc)
#pragma unroll
        for (int s = 0; s < 2; ++s)
          acc[tr + 4][tc] = __builtin_amdgcn_mfma_f32_16x16x32_bf16(
              af[tr][s], bfr[tc][s], acc[tr + 4][tc], 0, 0, 0);
    __builtin_amdgcn_s_setprio(0);
    SB(); BAR();

    // ---- phase 3: remaining MFMAs; counted drain of B(t+1) ----
    __builtin_amdgcn_s_setprio(1);
#pragma unroll
    for (int tr = 0; tr < 4; ++tr)
#pragma unroll
      for (int tc = 2; tc < 4; ++tc)
#pragma unroll
        for (int s = 0; s < 2; ++s)
          acc[tr + 4][tc] = __builtin_amdgcn_mfma_f32_16x16x32_bf16(
              af[tr][s], bfr[tc][s], acc[tr + 4][tc], 0, 0, 0);
    __builtin_amdgcn_s_setprio(0);
    SB();
    if (t < 7) {
      if (t < 6) { WAIT_VM8(); }     // B(t+1) done; A(t+2)x8 stays in flight
      else       { WAIT_VM0(); }     // t==6: nothing else outstanding
      SB();
      BAR(); SB();
    }
  }

  // ------------- epilogue: e = tanh(acc + S[b][n]); dot with v; atomics -------------
  const int bb = rb >> 3;              // 256 rows/block, 2048 rows/batch
  const float* Srow = S + bb * 512;
  float sv[4], vv[4];
#pragma unroll
  for (int tc = 0; tc < 4; ++tc) {
    int n = col0 + wc * 64 + tc * 16 + l15;
    sv[tc] = Srow[n];
    vv[tc] = vd[n];
  }
#pragma unroll
  for (int tr = 0; tr < 8; ++tr) {
#pragma unroll
    for (int r = 0; r < 4; ++r) {
      float ssum = 0.f;
#pragma unroll
      for (int tc = 0; tc < 4; ++tc) {
        float x = acc[tr][tc][r] + sv[tc];
        x = fminf(15.f, fmaxf(-15.f, x));
        float e2 = __expf(2.f * x);
        float e = (e2 - 1.f) / (e2 + 1.f);  // tanh
        ssum += e * vv[tc];
      }
      ssum += __shfl_xor(ssum, 1);
      ssum += __shfl_xor(ssum, 2);
      ssum += __shfl_xor(ssum, 4);
      ssum += __shfl_xor(ssum, 8);
      if (l15 == 0) {
        int row = row0 + wr * 128 + tr * 16 + q * 4 + r;
        atomicAdd(lout + row, ssum);
      }
    }
  }
}

// ---------------------------------------------------------------------------
// Kernel 3: softmax over T=2048, in place on d_out. One block per batch.
// ---------------------------------------------------------------------------
extern "C" __global__ __launch_bounds__(256) void softmax_t(float* __restrict__ l)
{
  int b = blockIdx.x, tid = threadIdx.x;
  int wave = tid >> 6, lane = tid & 63;
  float* row = l + (size_t)b * 2048;
  float v[8];
  float mx = -3.4e38f;
#pragma unroll
  for (int i = 0; i < 8; ++i) { v[i] = row[tid + i * 256]; mx = fmaxf(mx, v[i]); }
#pragma unroll
  for (int m = 1; m < 64; m <<= 1) mx = fmaxf(mx, __shfl_xor(mx, m));
  __shared__ float red[8];
  if (lane == 0) red[wave] = mx;
  __syncthreads();
  mx = fmaxf(fmaxf(red[0], red[1]), fmaxf(red[2], red[3]));
  float s = 0.f;
#pragma unroll
  for (int i = 0; i < 8; ++i) { v[i] = __expf(v[i] - mx); s += v[i]; }
#pragma unroll
  for (int m = 1; m < 64; m <<= 1) s += __shfl_xor(s, m);
  if (lane == 0) red[4 + wave] = s;
  __syncthreads();
  s = red[4] + red[5] + red[6] + red[7];
  float inv = 1.f / s;
#pragma unroll
  for (int i = 0; i < 8; ++i) row[tid + i * 256] = v[i] * inv;
}

// ---------------------------------------------------------------------------
extern "C" void kernel_launch(void* const* d_in, const int* in_sizes, int n_in,
                              void* d_out, int out_size, void* d_ws, size_t ws_size,
                              hipStream_t stream) {
  const float* hidden = (const float*)d_in[0];
  const float* cell   = (const float*)d_in[1];
  const float* enc    = (const float*)d_in[2];
  const float* W_d    = (const float*)d_in[3];
  const float* b_wd   = (const float*)d_in[4];
  const float* U_d    = (const float*)d_in[5];
  const float* b_ud   = (const float*)d_in[6];
  const float* v_d    = (const float*)d_in[7];
  // d_in[8] = b_vd: constant shift over T -> softmax-invariant, unused.
  float* out = (float*)d_out;                     // logits then softmax, in place
  float* S   = (float*)d_ws;                      // 64*512 fp32   = 128 KB
  short* UT  = (short*)((char*)d_ws + 32768 * sizeof(float));  // 512 KB image

  hipLaunchKernelGGL(prep_kernel, dim3(512), dim3(256), 0, stream,
                     hidden, cell, W_d, b_wd, U_d, b_ud, S, UT, out);
  hipLaunchKernelGGL(attn_gemm, dim3(1024), dim3(512), 0, stream,
                     enc, UT, S, v_d, out);
  hipLaunchKernelGGL(softmax_t, dim3(64), dim3(256), 0, stream, out);
}